// Round 1
// baseline (232.389 us; speedup 1.0000x reference)
//
#include <hip/hip_runtime.h>

// ThetaGammaCLEVRN: the phase network is dead code (output uses only
// amplitudes; amplitude ODE is phase-independent; theta amps stay == 1).
// Reduced computation per element e:
//   sf[16]  = mean_o scene[e,o,:]
//   g0[64]  = sigmoid(sf @ Ws + bs)
//   ga[64]  = 20 Euler steps of g += DT * g * (1 - g^2)
//   h[64]   = relu(ga @ W1[16:80] + query[e] @ Weff + beff)
//   logits  = h @ W2 + b2 ;  out = log_softmax(logits)
// where Weff = Wq @ W1[80:144]  (60x64)
//       beff = b1 + sum_{k<16} W1[k,:] + bq @ W1[80:144]
// Never reads theta/gamma phase/freq arrays (42 MB saved).

#define WAVES_PER_BLK 4
#define ELEMS_PER_WAVE 16

// ---- prep: Weff (60x64) and beff (64) into ws[0..3903] ----
__global__ void prep_kernel(const float* __restrict__ Wq,
                            const float* __restrict__ bq,
                            const float* __restrict__ W1,
                            const float* __restrict__ b1,
                            float* __restrict__ ws) {
    int gid = blockIdx.x * blockDim.x + threadIdx.x;
    if (gid < 3840) {
        int d = gid >> 6, j = gid & 63;
        float acc = 0.f;
        #pragma unroll 16
        for (int k = 0; k < 64; ++k)
            acc = fmaf(Wq[d * 64 + k], W1[(80 + k) * 64 + j], acc);
        ws[gid] = acc;
    } else if (gid < 3904) {
        int j = gid - 3840;
        float acc = b1[j];
        #pragma unroll
        for (int k = 0; k < 16; ++k) acc += W1[k * 64 + j];
        #pragma unroll 16
        for (int k = 0; k < 64; ++k)
            acc = fmaf(bq[k], W1[(80 + k) * 64 + j], acc);
        ws[gid] = acc;
    }
}

// ---- fused main kernel: one wave per element ----
__global__ __launch_bounds__(256, 4) void fused_kernel(
    const float* __restrict__ scene,   // (B,10,16)
    const float* __restrict__ query,   // (B,60)
    const float* __restrict__ Ws,      // (16,64)
    const float* __restrict__ bs,      // (64)
    const float* __restrict__ W1,      // (144,64)
    const float* __restrict__ W2,      // (64,2)
    const float* __restrict__ b2,      // (2)
    const float* __restrict__ wsbuf,   // Weff(3840) + beff(64)
    float* __restrict__ out)           // (B,2)
{
    // Transposed stacked weights WT[j][k], k = 0..123 ([W1g(64) ; Weff(60)]),
    // row stride 128 words, 16B-chunk XOR swizzle: chunk' = chunk ^ (j&7).
    // -> 8 consecutive lanes tile all 32 banks on ds_read_b128.
    __shared__ float WT[64 * 128];                 // 32 KB
    __shared__ float act[WAVES_PER_BLK][128];      // 2 KB (per-wave slot)

    const int t    = threadIdx.x;
    const int lane = t & 63;
    const int wv   = t >> 6;

    // stage WT (once per block; weights are L2-resident)
    #pragma unroll
    for (int i = 0; i < 31; ++i) {
        int idx = t + i * 256;                     // 0..7935 = 124*64
        int k = idx >> 6, j = idx & 63;
        float v = (k < 64) ? W1[(16 + k) * 64 + j] : wsbuf[(k - 64) * 64 + j];
        WT[j * 128 + ((((k >> 2) ^ (j & 7)) << 2) | (k & 3))] = v;
    }

    // per-lane loop invariants in registers
    float wsr[16];
    #pragma unroll
    for (int d = 0; d < 16; ++d) wsr[d] = Ws[d * 64 + lane];
    const float bs_r   = bs[lane];
    const float beff_r = wsbuf[3840 + lane];
    const float w2a = W2[lane * 2 + 0];
    const float w2b = W2[lane * 2 + 1];
    const float b2a = b2[0];
    const float b2b = b2[1];
    __syncthreads();

    const int waveId = blockIdx.x * WAVES_PER_BLK + wv;

    for (int it = 0; it < ELEMS_PER_WAVE; ++it) {
        const int e = waveId * ELEMS_PER_WAVE + it;

        // ---- scene mean: 160 floats, coalesced; lane holds sf[lane&15] ----
        const float* sp = scene + (size_t)e * 160;
        float s = sp[lane] + sp[lane + 64];
        if (lane < 32) s += sp[lane + 128];
        s += __shfl_xor(s, 16);
        s += __shfl_xor(s, 32);
        const float sf = s * 0.1f;                 // mean over 10 objects

        // ---- g0 = sigmoid(sf @ Ws + bs) ----
        float x = bs_r;
        #pragma unroll
        for (int d = 0; d < 16; ++d)
            x = fmaf(__shfl(sf, d), wsr[d], x);
        float g = 1.0f / (1.0f + __expf(-x));

        // ---- Stuart-Landau amplitude ODE, 20 Euler steps ----
        #pragma unroll
        for (int n = 0; n < 20; ++n) {
            float g2 = g * g;
            g = fmaf(0.01f, g * (1.0f - g2), g);
        }

        // ---- activations into per-wave LDS slot (wave-synchronous) ----
        act[wv][lane] = g;
        if (lane < 60) act[wv][64 + lane] = query[(size_t)e * 60 + lane];

        // ---- h[lane] = beff + sum_k act[k] * WT[lane][k], k<124 ----
        float a0 = beff_r, a1 = 0.f, a2 = 0.f, a3 = 0.f;
        #pragma unroll
        for (int c = 0; c < 31; ++c) {
            const float4 av = *(const float4*)&act[wv][c << 2];  // uniform -> broadcast
            const float4 wt = *(const float4*)&WT[lane * 128 + ((c ^ (lane & 7)) << 2)];
            a0 = fmaf(av.x, wt.x, a0);
            a1 = fmaf(av.y, wt.y, a1);
            a2 = fmaf(av.z, wt.z, a2);
            a3 = fmaf(av.w, wt.w, a3);
        }
        const float h = fmaxf((a0 + a1) + (a2 + a3), 0.f);

        // ---- logits = h @ W2 + b2 (wave reduction), log_softmax ----
        float l0 = h * w2a;
        float l1 = h * w2b;
        #pragma unroll
        for (int m = 1; m < 64; m <<= 1) {
            l0 += __shfl_xor(l0, m);
            l1 += __shfl_xor(l1, m);
        }
        l0 += b2a; l1 += b2b;
        const float mx = fmaxf(l0, l1);
        const float lz = mx + __logf(__expf(l0 - mx) + __expf(l1 - mx));
        if (lane == 0) {
            float2 o = { l0 - lz, l1 - lz };
            *(float2*)(out + (size_t)e * 2) = o;
        }
    }
}

extern "C" void kernel_launch(void* const* d_in, const int* in_sizes, int n_in,
                              void* d_out, int out_size, void* d_ws, size_t ws_size,
                              hipStream_t stream) {
    const float* scene = (const float*)d_in[0];
    const float* query = (const float*)d_in[1];
    // d_in[2..5] = theta/gamma phase & freq: provably unused by the output
    const float* Ws = (const float*)d_in[6];
    const float* bs = (const float*)d_in[7];
    const float* Wq = (const float*)d_in[8];
    const float* bq = (const float*)d_in[9];
    const float* W1 = (const float*)d_in[10];
    const float* b1 = (const float*)d_in[11];
    const float* W2 = (const float*)d_in[12];
    const float* b2 = (const float*)d_in[13];
    float* out = (float*)d_out;
    float* ws  = (float*)d_ws;   // needs 3904 floats = 15.6 KB

    const int B = in_sizes[0] / 160;                 // 65536
    const int nblk = B / (WAVES_PER_BLK * ELEMS_PER_WAVE);  // 1024

    prep_kernel<<<16, 256, 0, stream>>>(Wq, bq, W1, b1, ws);
    fused_kernel<<<nblk, 256, 0, stream>>>(scene, query, Ws, bs, W1, W2, b2, ws, out);
}

// Round 2
// 78.439 us; speedup vs baseline: 2.9627x; 2.9627x over previous
//
#include <hip/hip_runtime.h>

// ThetaGammaCLEVRN: phase network is dead code (output uses only amplitudes;
// amplitude ODE is phase-independent; theta amps stay == 1). Per element e:
//   sf[16]  = mean_o scene[e,o,:]
//   g0[64]  = sigmoid(sf @ Ws + bs)
//   ga[64]  = 20 Euler steps of g += DT * g * (1 - g^2)
//   h[64]   = relu(ga @ W1[16:80] + query[e] @ Weff + beff)
//   out     = log_softmax(h @ W2 + b2)
// Weff = Wq @ W1[80:144] (60x64); beff = b1 + sum_{k<16} W1[k,:] + bq @ W1[80:144].
//
// R2 design: one wave per element-group of 16. All per-element data moves as
// float4 (lanes 0..39 scene row, 40..54 query row). WT (124 x fp32) lives in
// per-lane REGISTERS (lane = hidden unit j); activations broadcast from a
// 128-float LDS slot. Manual next-element prefetch; coalesced final store.

#define EPW 16  // elements per wave

__global__ void prep_kernel(const float* __restrict__ Wq,
                            const float* __restrict__ bq,
                            const float* __restrict__ W1,
                            const float* __restrict__ b1,
                            float* __restrict__ ws) {
    int gid = blockIdx.x * blockDim.x + threadIdx.x;
    if (gid < 3840) {
        int d = gid >> 6, j = gid & 63;
        float acc = 0.f;
        #pragma unroll 16
        for (int k = 0; k < 64; ++k)
            acc = fmaf(Wq[d * 64 + k], W1[(80 + k) * 64 + j], acc);
        ws[gid] = acc;
    } else if (gid < 3904) {
        int j = gid - 3840;
        float acc = b1[j];
        #pragma unroll
        for (int k = 0; k < 16; ++k) acc += W1[k * 64 + j];
        #pragma unroll 16
        for (int k = 0; k < 64; ++k)
            acc = fmaf(bq[k], W1[(80 + k) * 64 + j], acc);
        ws[gid] = acc;
    }
}

__global__ __launch_bounds__(256, 2) void fused_kernel(
    const float* __restrict__ scene,   // (B,10,16)
    const float* __restrict__ query,   // (B,60)
    const float* __restrict__ Ws,      // (16,64)
    const float* __restrict__ bs,      // (64)
    const float* __restrict__ W1,      // (144,64)
    const float* __restrict__ W2,      // (64,2)
    const float* __restrict__ b2,      // (2)
    const float* __restrict__ wsbuf,   // Weff(3840) + beff(64)
    float* __restrict__ out)           // (B,2)
{
    __shared__ float act[4][128];      // per-wave activation slot (2 KB)

    const int t    = threadIdx.x;
    const int lane = t & 63;
    const int wv   = t >> 6;
    const int waveId = blockIdx.x * 4 + wv;
    const int e0 = waveId * EPW;

    // ---- per-lane register weights: lane owns hidden unit j = lane ----
    float wt[124];
    #pragma unroll
    for (int k = 0; k < 64; ++k) wt[k] = W1[(16 + k) * 64 + lane];
    #pragma unroll
    for (int k = 0; k < 60; ++k) wt[64 + k] = wsbuf[k * 64 + lane];
    float wsr[16];
    #pragma unroll
    for (int d = 0; d < 16; ++d) wsr[d] = 0.1f * Ws[d * 64 + lane];  // fold mean 1/10
    const float bs_r   = bs[lane];
    const float beff_r = wsbuf[3840 + lane];
    const float w2a = W2[lane * 2 + 0];
    const float w2b = W2[lane * 2 + 1];
    const float b2a = b2[0];
    const float b2b = b2[1];

    const int ql = lane - 40;

    // ---- prefetch element e0 ----
    float4 sv = {0.f, 0.f, 0.f, 0.f};
    float4 qv = {0.f, 0.f, 0.f, 0.f};
    if (lane < 40)      sv = *(const float4*)(scene + (size_t)e0 * 160 + 4 * lane);
    else if (lane < 55) qv = *(const float4*)(query + (size_t)e0 * 60 + 4 * ql);

    float r0 = 0.f, r1 = 0.f;

    #pragma unroll 1
    for (int it = 0; it < EPW; ++it) {
        const int e = e0 + it;

        // ---- prefetch next element (uniform branch) ----
        float4 svn = {0.f, 0.f, 0.f, 0.f};
        float4 qvn = {0.f, 0.f, 0.f, 0.f};
        if (it < EPW - 1) {
            if (lane < 40)      svn = *(const float4*)(scene + (size_t)(e + 1) * 160 + 4 * lane);
            else if (lane < 55) qvn = *(const float4*)(query + (size_t)(e + 1) * 60 + 4 * ql);
        }

        // ---- scene object-sum: butterfly over the 16-lane groups {l mod 4} ----
        // lane l (<40) comp j holds scene[e][4l+j]; flat idx i: d = i&15, o = i>>4.
        // Summing lanes {l == l0 (mod 4)} gives sum over o for d = (4*l0+j)&15.
        float4 s4 = sv;
        #pragma unroll
        for (int m = 4; m <= 32; m <<= 1) {
            s4.x += __shfl_xor(s4.x, m);
            s4.y += __shfl_xor(s4.y, m);
            s4.z += __shfl_xor(s4.z, m);
            s4.w += __shfl_xor(s4.w, m);
        }

        // ---- g0 = sigmoid(sf @ Ws + bs); sf[4l+j] at lane l comp j, l<4 ----
        float x = bs_r;
        #pragma unroll
        for (int l = 0; l < 4; ++l) {
            x = fmaf(__shfl(s4.x, l), wsr[4 * l + 0], x);
            x = fmaf(__shfl(s4.y, l), wsr[4 * l + 1], x);
            x = fmaf(__shfl(s4.z, l), wsr[4 * l + 2], x);
            x = fmaf(__shfl(s4.w, l), wsr[4 * l + 3], x);
        }
        float g = 1.0f / (1.0f + __expf(-x));

        // ---- Stuart-Landau amplitude ODE, 20 Euler steps ----
        #pragma unroll
        for (int n = 0; n < 20; ++n) {
            float g2 = g * g;
            g = fmaf(0.01f, g * (1.0f - g2), g);
        }

        // ---- stage activations (wave-synchronous, no barrier needed) ----
        act[wv][lane] = g;
        if (lane >= 40 && lane < 55) *(float4*)&act[wv][64 + 4 * ql] = qv;

        // ---- h[lane] = beff + sum_{k<124} act[k] * wt[k] ----
        float a0 = beff_r, a1 = 0.f, a2 = 0.f, a3 = 0.f;
        #pragma unroll
        for (int c = 0; c < 31; ++c) {
            const float4 av = *(const float4*)&act[wv][c << 2];  // uniform -> broadcast
            a0 = fmaf(av.x, wt[4 * c + 0], a0);
            a1 = fmaf(av.y, wt[4 * c + 1], a1);
            a2 = fmaf(av.z, wt[4 * c + 2], a2);
            a3 = fmaf(av.w, wt[4 * c + 3], a3);
        }
        const float h = fmaxf((a0 + a1) + (a2 + a3), 0.f);

        // ---- logits + log_softmax; full-wave butterfly leaves sum in all lanes ----
        float l0 = h * w2a;
        float l1 = h * w2b;
        #pragma unroll
        for (int m = 1; m < 64; m <<= 1) {
            l0 += __shfl_xor(l0, m);
            l1 += __shfl_xor(l1, m);
        }
        l0 += b2a; l1 += b2b;
        const float mx = fmaxf(l0, l1);
        const float lz = mx + __logf(__expf(l0 - mx) + __expf(l1 - mx));
        if (lane == it) { r0 = l0 - lz; r1 = l1 - lz; }

        sv = svn; qv = qvn;
    }

    // ---- coalesced store: lanes 0..15 write their element's float2 (128 B) ----
    if (lane < EPW) {
        float2 o = { r0, r1 };
        *(float2*)(out + (size_t)(e0 + lane) * 2) = o;
    }
}

extern "C" void kernel_launch(void* const* d_in, const int* in_sizes, int n_in,
                              void* d_out, int out_size, void* d_ws, size_t ws_size,
                              hipStream_t stream) {
    const float* scene = (const float*)d_in[0];
    const float* query = (const float*)d_in[1];
    // d_in[2..5] = theta/gamma phase & freq: provably unused by the output
    const float* Ws = (const float*)d_in[6];
    const float* bs = (const float*)d_in[7];
    const float* Wq = (const float*)d_in[8];
    const float* bq = (const float*)d_in[9];
    const float* W1 = (const float*)d_in[10];
    const float* b1 = (const float*)d_in[11];
    const float* W2 = (const float*)d_in[12];
    const float* b2 = (const float*)d_in[13];
    float* out = (float*)d_out;
    float* ws  = (float*)d_ws;   // 3904 floats = 15.6 KB

    const int B = in_sizes[0] / 160;                 // 65536
    const int nblk = B / (4 * EPW);                  // 1024

    prep_kernel<<<16, 256, 0, stream>>>(Wq, bq, W1, b1, ws);
    fused_kernel<<<nblk, 256, 0, stream>>>(scene, query, Ws, bs, W1, W2, b2, ws, out);
}

// Round 4
// 37.164 us; speedup vs baseline: 6.2530x; 2.1106x over previous
//
#include <hip/hip_runtime.h>

// ThetaGammaCLEVRN — element-per-THREAD formulation.
// Math reduction (phase network is dead code; theta amps stay exactly 1):
//   sf[16] = sum_o scene[e,o,:]          (0.1 mean factor folded into Ws)
//   x[j]   = sf @ (0.1*Ws) + bs ; ga[j] = F20(sigmoid(x[j]))  via 512-entry LUT
//   h[j]   = relu(ga @ W1[16:80] + query @ Weff + beff)
//   out    = log_softmax(h @ W2 + b2)
// Weff = Wq @ W1[80:144]; beff = b1 + sum_{k<16} W1[k,:] + bq @ W1[80:144].
//
// Per block: 256 elements. LDS (61 KB static): packed half2 weights (uniform
// broadcast reads), fp32 LUT, transposed fp16 activations (pitch 257 ->
// conflict-free per-lane reads). Inner loop: v_dot2_f32_f16 (2 MAC/instr).

typedef __fp16 h2_t __attribute__((ext_vector_type(2)));
union H2U { unsigned u; h2_t h; float f; };

__device__ __forceinline__ unsigned pk(float a, float b) {
#if __has_builtin(__builtin_amdgcn_cvt_pkrtz)
    H2U v; v.h = __builtin_amdgcn_cvt_pkrtz(a, b);
#else
    H2U v; v.h = (h2_t){(__fp16)a, (__fp16)b};
#endif
    return v.u;
}
__device__ __forceinline__ h2_t uh(unsigned x) { H2U v; v.u = x; return v.h; }
__device__ __forceinline__ float dot2(h2_t a, h2_t b, float c) {
#if __has_builtin(__builtin_amdgcn_fdot2)
    return __builtin_amdgcn_fdot2(a, b, c, false);
#else
    return c + (float)a.x * (float)b.x + (float)a.y * (float)b.y;
#endif
}
__device__ __forceinline__ float F20(float g) {
    #pragma unroll
    for (int n = 0; n < 20; ++n) {
        float g2 = g * g;
        float u  = g * (1.0f - g2);
        g = fmaf(0.01f, u, g);
    }
    return g;
}

// ws layout (fp32 words):
//   0    : Wh   [62*64]  half2(W[2kp][j], W[2kp+1][j]) of stacked [W1g;Weff]
//   3968 : Wsh  [64*8]   half2(0.1*Ws[2dp][j], 0.1*Ws[2dp+1][j]), idx j*8+dp
//   4480 : T2   [512*2]  (F(sig(x_i)), F(sig(x_{i+1}))-F(sig(x_i))), x_i=i/64-4
//   5504 : beff [64]
//   5568 : W2f2 [128]
//   5696 : bs   [64]
//   5760 : b2   [2]      -> total 5762 words
#define CW 5762

__global__ void prep_kernel(const float* __restrict__ Ws,
                            const float* __restrict__ bs,
                            const float* __restrict__ Wq,
                            const float* __restrict__ bq,
                            const float* __restrict__ W1,
                            const float* __restrict__ b1,
                            const float* __restrict__ W2,
                            const float* __restrict__ b2,
                            float* __restrict__ ws) {
    unsigned* wsu = (unsigned*)ws;
    int gid = blockIdx.x * 256 + threadIdx.x;
    if (gid < 3968) {                        // Wh
        int kp = gid >> 6, j = gid & 63;
        float a, b;
        if (kp < 32) {
            a = W1[(16 + 2 * kp) * 64 + j];
            b = W1[(17 + 2 * kp) * 64 + j];
        } else {
            int qd = 2 * (kp - 32);
            float s0 = 0.f, s1 = 0.f;
            #pragma unroll 16
            for (int c = 0; c < 64; ++c) {
                float w = W1[(80 + c) * 64 + j];
                s0 = fmaf(Wq[qd * 64 + c], w, s0);
                s1 = fmaf(Wq[(qd + 1) * 64 + c], w, s1);
            }
            a = s0; b = s1;
        }
        wsu[gid] = pk(a, b);
    } else if (gid >= 4096 && gid < 4608) {  // Wsh
        int w = gid - 4096, j = w >> 3, dp = w & 7;
        wsu[3968 + w] = pk(0.1f * Ws[(2 * dp) * 64 + j],
                           0.1f * Ws[(2 * dp + 1) * 64 + j]);
    } else if (gid >= 5120 && gid < 5632) {  // LUT
        int i = gid - 5120;
        float x0 = (float)i * 0.015625f - 4.0f;
        float x1 = x0 + 0.015625f;
        float F0 = F20(1.0f / (1.0f + expf(-x0)));
        float F1 = F20(1.0f / (1.0f + expf(-x1)));
        ws[4480 + 2 * i]     = F0;
        ws[4480 + 2 * i + 1] = F1 - F0;
    } else if (gid >= 5632 && gid < 5696) {  // beff
        int j = gid - 5632;
        float acc = b1[j];
        #pragma unroll
        for (int k = 0; k < 16; ++k) acc += W1[k * 64 + j];
        #pragma unroll 16
        for (int c = 0; c < 64; ++c)
            acc = fmaf(bq[c], W1[(80 + c) * 64 + j], acc);
        ws[5504 + j] = acc;
    } else if (gid >= 5696 && gid < 5824) {  // W2 copy
        int i = gid - 5696;
        ws[5568 + i] = W2[i];
    } else if (gid >= 5824 && gid < 5888) {  // bs copy
        int j = gid - 5824;
        ws[5696 + j] = bs[j];
    } else if (gid == 5888) {
        ws[5760] = b2[0];
        ws[5761] = b2[1];
    }
}

__global__ __launch_bounds__(256, 1) void fused_kernel(
    const float* __restrict__ scene,   // (B,10,16)
    const float* __restrict__ query,   // (B,60)
    const float* __restrict__ wsbuf,   // CW words, see layout
    float* __restrict__ out)           // (B,2)
{
    __shared__ __align__(16) float cbuf[CW];       // 23.0 KB constants
    __shared__ unsigned sfT2[8 * 257];             //  8.2 KB  sf pairs (f16)
    __shared__ unsigned qT2[30 * 257];             // 30.8 KB  query pairs (f16)

    const int t  = threadIdx.x;
    const int eb = blockIdx.x << 8;

    // ---- stage constants (coalesced, linear) ----
    for (int i = t; i < CW; i += 256) cbuf[i] = wsbuf[i];

    // ---- stage scene -> sf sums, transposed fp16 pairs ----
    #pragma unroll
    for (int p = 0; p < 4; ++p) {
        const int el = (p << 6) + (t >> 2);
        const int c4 = t & 3;
        const float4* sp = (const float4*)scene + (size_t)(eb + el) * 40 + c4;
        float4 acc = sp[0];
        #pragma unroll
        for (int o = 1; o < 10; ++o) {
            float4 v = sp[o * 4];
            acc.x += v.x; acc.y += v.y; acc.z += v.z; acc.w += v.w;
        }
        sfT2[(2 * c4) * 257 + el]     = pk(acc.x, acc.y);
        sfT2[(2 * c4 + 1) * 257 + el] = pk(acc.z, acc.w);
    }

    // ---- stage query, transposed fp16 pairs ----
    #pragma unroll
    for (int i = 0; i < 15; ++i) {
        const int q4 = t + (i << 8);
        const int el = q4 / 15, kq = q4 % 15;
        float4 qv = ((const float4*)query)[(size_t)(eb + el) * 15 + kq];
        qT2[(2 * kq) * 257 + el]     = pk(qv.x, qv.y);
        qT2[(2 * kq + 1) * 257 + el] = pk(qv.z, qv.w);
    }
    __syncthreads();

    // ================= per-thread compute: element E = eb + t ==============
    h2_t sf[8];
    #pragma unroll
    for (int dp = 0; dp < 8; ++dp) sf[dp] = uh(sfT2[dp * 257 + t]);

    float h[64];
    #pragma unroll
    for (int j = 0; j < 64; ++j) h[j] = cbuf[5504 + j];

    const float2* T2 = (const float2*)&cbuf[4480];

    // ---- k-pairs 0..31: gamma units (computed on the fly) ----
    #pragma unroll 1
    for (int kp = 0; kp < 32; ++kp) {
        const uint4* wrow = (const uint4*)&cbuf[kp << 6];          // uniform
        const uint4* wsr  = (const uint4*)&cbuf[3968 + (kp << 4)]; // uniform
        const uint4 wa = wsr[0], wb = wsr[1];   // Wsh row j=2kp
        const uint4 wc = wsr[2], wd = wsr[3];   // Wsh row j=2kp+1
        float x0 = cbuf[5696 + 2 * kp];
        float x1 = cbuf[5696 + 2 * kp + 1];
        x0 = dot2(sf[0], uh(wa.x), x0); x0 = dot2(sf[1], uh(wa.y), x0);
        x0 = dot2(sf[2], uh(wa.z), x0); x0 = dot2(sf[3], uh(wa.w), x0);
        x0 = dot2(sf[4], uh(wb.x), x0); x0 = dot2(sf[5], uh(wb.y), x0);
        x0 = dot2(sf[6], uh(wb.z), x0); x0 = dot2(sf[7], uh(wb.w), x0);
        x1 = dot2(sf[0], uh(wc.x), x1); x1 = dot2(sf[1], uh(wc.y), x1);
        x1 = dot2(sf[2], uh(wc.z), x1); x1 = dot2(sf[3], uh(wc.w), x1);
        x1 = dot2(sf[4], uh(wd.x), x1); x1 = dot2(sf[5], uh(wd.y), x1);
        x1 = dot2(sf[6], uh(wd.z), x1); x1 = dot2(sf[7], uh(wd.w), x1);
        // ga pair via LUT (sigmoid + 20-step Euler fused)
        float u0 = fminf(fmaxf(fmaf(x0, 64.0f, 256.0f), 0.0f), 511.0f);
        float u1 = fminf(fmaxf(fmaf(x1, 64.0f, 256.0f), 0.0f), 511.0f);
        int   i0 = (int)u0, i1 = (int)u1;
        float2 e0 = T2[i0], e1 = T2[i1];
        float g0 = fmaf(u0 - (float)i0, e0.y, e0.x);
        float g1 = fmaf(u1 - (float)i1, e1.y, e1.x);
        H2U a2u; a2u.u = pk(g0, g1);
        const h2_t a2 = a2u.h;
        #pragma unroll
        for (int jq = 0; jq < 16; ++jq) {
            uint4 w = wrow[jq];
            h[4 * jq + 0] = dot2(a2, uh(w.x), h[4 * jq + 0]);
            h[4 * jq + 1] = dot2(a2, uh(w.y), h[4 * jq + 1]);
            h[4 * jq + 2] = dot2(a2, uh(w.z), h[4 * jq + 2]);
            h[4 * jq + 3] = dot2(a2, uh(w.w), h[4 * jq + 3]);
        }
    }

    // ---- k-pairs 32..61: query dims (fp16 pairs from LDS, per-lane) ----
    #pragma unroll 1
    for (int kp = 0; kp < 30; ++kp) {
        const h2_t a2 = uh(qT2[kp * 257 + t]);
        const uint4* wrow = (const uint4*)&cbuf[(32 + kp) << 6];   // uniform
        #pragma unroll
        for (int jq = 0; jq < 16; ++jq) {
            uint4 w = wrow[jq];
            h[4 * jq + 0] = dot2(a2, uh(w.x), h[4 * jq + 0]);
            h[4 * jq + 1] = dot2(a2, uh(w.y), h[4 * jq + 1]);
            h[4 * jq + 2] = dot2(a2, uh(w.z), h[4 * jq + 2]);
            h[4 * jq + 3] = dot2(a2, uh(w.w), h[4 * jq + 3]);
        }
    }

    // ---- relu + logits + log_softmax ----
    float l0 = cbuf[5760], l1 = cbuf[5761];
    const float2* w2p = (const float2*)&cbuf[5568];
    #pragma unroll
    for (int j = 0; j < 64; ++j) {
        float hv = fmaxf(h[j], 0.0f);
        float2 w = w2p[j];
        l0 = fmaf(hv, w.x, l0);
        l1 = fmaf(hv, w.y, l1);
    }
    const float mx = fmaxf(l0, l1);
    const float lz = mx + __logf(__expf(l0 - mx) + __expf(l1 - mx));
    float2 o = { l0 - lz, l1 - lz };
    ((float2*)out)[eb + t] = o;
}

extern "C" void kernel_launch(void* const* d_in, const int* in_sizes, int n_in,
                              void* d_out, int out_size, void* d_ws, size_t ws_size,
                              hipStream_t stream) {
    const float* scene = (const float*)d_in[0];
    const float* query = (const float*)d_in[1];
    // d_in[2..5] = theta/gamma phase & freq: provably unused by the output
    const float* Ws = (const float*)d_in[6];
    const float* bs = (const float*)d_in[7];
    const float* Wq = (const float*)d_in[8];
    const float* bq = (const float*)d_in[9];
    const float* W1 = (const float*)d_in[10];
    const float* b1 = (const float*)d_in[11];
    const float* W2 = (const float*)d_in[12];
    const float* b2 = (const float*)d_in[13];
    float* out = (float*)d_out;
    float* ws  = (float*)d_ws;   // needs CW*4 = 23 KB

    const int B = in_sizes[0] / 160;   // 65536
    prep_kernel<<<24, 256, 0, stream>>>(Ws, bs, Wq, bq, W1, b1, W2, b2, ws);
    fused_kernel<<<B / 256, 256, 0, stream>>>(scene, query, ws, out);
}